// Round 4
// baseline (205.117 us; speedup 1.0000x reference)
//
#include <hip/hip_runtime.h>
#include <math.h>

constexpr int B = 2, H = 320, W = 512, D = 64;
constexpr int HW = H * W;
constexpr int R = 10;            // BLOCK // 2
constexpr int SEG = 80;          // output rows per cost block
constexpr int NSEG = H / SEG;    // 4
constexpr int RS = 548;          // vsbuf row stride (words): RS/4 == 137 == 1 (mod 8)
constexpr float EPS = 1e-12f;

// Normalize + pack into float4 planes: nrm4[((t*B+b)*2+side)*HW + hw] = (c0,c1,c2,0)
__global__ void k_norm(const float* __restrict__ x, const float* __restrict__ gt,
                       float4* __restrict__ nrm4) {
    int idx = blockIdx.x * blockDim.x + threadIdx.x;
    if (idx >= 2 * B * HW) return;
    int t = idx / (B * HW);
    int rem = idx - t * (B * HW);
    int b = rem / HW;
    int hw = rem - b * HW;
    const float* p = (t == 0 ? x : gt) + (size_t)b * 6 * HW + hw;
    float v0 = p[0],      v1 = p[HW],     v2 = p[2 * HW];
    float v3 = p[3 * HW], v4 = p[4 * HW], v5 = p[5 * HW];
    float n1 = fmaxf(sqrtf(v0 * v0 + v1 * v1 + v2 * v2), EPS);
    float n2 = fmaxf(sqrtf(v3 * v3 + v4 * v4 + v5 * v5), EPS);
    float4* q = nrm4 + (size_t)(t * B + b) * 2 * HW + hw;
    q[0]  = make_float4(v0 / n1, v1 / n1, v2 / n1, 0.f);
    q[HW] = make_float4(v3 / n2, v4 / n2, v5 / n2, 0.f);
}

// Fully-rolling 21x21 box-filtered SAD cost.
// Per 8-row superstep: hoist 8 ring reads -> 8 diffs (16 indep global loads)
// -> 8 ring writes -> serial-but-short vs chain -> vsbuf(write parity buf)
// -> ONE barrier -> horizontal rolling phase reads other parity buf.
__global__ __launch_bounds__(512, 2) void k_cost(const float4* __restrict__ nrm4,
                                                 float* __restrict__ cost, int t) {
    int blk = blockIdx.x;
    int combo = blk & 7;           // B*NSEG = 8 combos; blk%8 pins combo to one XCD
    int d = blk >> 3;
    int b = combo >> 2;
    int seg = combo & 3;
    int w = threadIdx.x;           // phase-1 column
    const float4* L4 = nrm4 + (size_t)(t * B + b) * 2 * HW;
    const float4* R4 = L4 + HW;
    const bool val = (w >= d);
    const int wr = val ? (w - d) : 0;
    const int h0 = seg * SEG;

    __shared__ float ring[21][W];     // diff delay line, strictly per-column
    __shared__ float vsb[2][8][RS];   // double-buffered vs snapshots (+10 halo each side)

    {   // zero halo pads of both parity buffers once
        int j = w >> 6, k = w & 63;
        if (k < 10)      { vsb[0][j][k] = 0.f;       vsb[1][j][k] = 0.f; }
        else if (k < 20) { vsb[0][j][512 + k] = 0.f; vsb[1][j][512 + k] = 0.f; }
    }

    auto diff = [&](int h) -> float {
        float4 l = L4[(size_t)h * W + w];
        if (val) {
            float4 r = R4[(size_t)h * W + wr];
            return fabsf(l.x - r.x) + fabsf(l.y - r.y) + fabsf(l.z - r.z);
        }
        return fabsf(l.x) + fabsf(l.y) + fabsf(l.z);  // r_shift == 0 when invalid
    };

    // Warm-up: rows [h0-10, h0+9] -> ring slots 0..19; slot 20 = row h0-11 (zero).
    float vs = 0.f;
    for (int k = 0; k < 20; ++k) {
        int h = h0 - R + k;
        float dv0 = (h >= 0) ? diff(h) : 0.f;
        ring[k][w] = dv0;
        vs += dv0;
    }
    ring[20][w] = 0.f;

    float* cp = cost + ((size_t)(b * D + d) * H) * W;
    const int cc = threadIdx.x >> 3;   // phase-2 col-run (0..63)
    const int jj = threadIdx.x & 7;    // phase-2 row slot (0..7)

    int slot0 = 20;                    // ring slot for first row of superstep
    for (int ss = 0; ss < SEG / 8; ++ss) {
        int sl[8];
        float dold[8], dv[8];
#pragma unroll
        for (int j = 0; j < 8; ++j) { int s2 = slot0 + j; if (s2 >= 21) s2 -= 21; sl[j] = s2; }
#pragma unroll
        for (int j = 0; j < 8; ++j) dold[j] = ring[sl[j]][w];     // 8 indep LDS reads
#pragma unroll
        for (int j = 0; j < 8; ++j) {                             // 16 indep global loads
            int hn = h0 + ss * 8 + j + R;
            dv[j] = (hn < H) ? diff(hn) : 0.f;
        }
#pragma unroll
        for (int j = 0; j < 8; ++j) ring[sl[j]][w] = dv[j];       // writes after all reads
        float* vrow = &vsb[ss & 1][0][0];
#pragma unroll
        for (int j = 0; j < 8; ++j) { vs += dv[j] - dold[j]; vrow[j * RS + 10 + w] = vs; }
        __syncthreads();
        // phase 2: 28-float window -> 8 outputs (other threads already start next phase-1
        // into the opposite parity buffer after this barrier)
        const float* vp = &vsb[ss & 1][jj][8 * cc];
        float wnd[28];
#pragma unroll
        for (int q = 0; q < 7; ++q) {
            float4 v4 = *(const float4*)(vp + 4 * q);
            wnd[4 * q] = v4.x; wnd[4 * q + 1] = v4.y;
            wnd[4 * q + 2] = v4.z; wnd[4 * q + 3] = v4.w;
        }
        float o = 0.f;
#pragma unroll
        for (int k = 0; k < 21; ++k) o += wnd[k];
        float out[8];
        out[0] = o;
#pragma unroll
        for (int k = 1; k < 8; ++k) { o += wnd[20 + k] - wnd[k - 1]; out[k] = o; }
        float* op = cp + (size_t)(h0 + ss * 8 + jj) * W + 8 * cc;
        *(float4*)(op)     = make_float4(out[0], out[1], out[2], out[3]);
        *(float4*)(op + 4) = make_float4(out[4], out[5], out[6], out[7]);
        slot0 += 8; if (slot0 >= 21) slot0 -= 21;
    }
}

// argmin t=0: one pixel per thread (2560 blocks -> latency hidden by occupancy).
__global__ void k_argmin0(const float* __restrict__ cost, float* __restrict__ disp) {
    int idx = blockIdx.x * 256 + threadIdx.x;
    if (idx >= B * HW) return;
    int b = idx / HW, hw = idx - b * HW;
    const float* cp = cost + (size_t)b * D * HW + hw;
    float best = cp[0]; int bd = 0;
#pragma unroll 16
    for (int d = 1; d < D; ++d) {
        float v = cp[(size_t)d * HW];
        if (v < best) { best = v; bd = d; }   // strict <: lowest d wins (jnp.argmin)
    }
    disp[idx] = (float)bd;
}

// argmin t=1 fused with |d1-d0| and per-block partial sum.
__global__ void k_argmin1(const float* __restrict__ cost, const float* __restrict__ disp0,
                          float* __restrict__ part) {
    int idx = blockIdx.x * 256 + threadIdx.x;
    float s = 0.f;
    if (idx < B * HW) {
        int b = idx / HW, hw = idx - b * HW;
        const float* cp = cost + (size_t)b * D * HW + hw;
        float best = cp[0]; int bd = 0;
#pragma unroll 16
        for (int d = 1; d < D; ++d) {
            float v = cp[(size_t)d * HW];
            if (v < best) { best = v; bd = d; }
        }
        s = fabsf((float)bd - disp0[idx]);
    }
    __shared__ float sm[256];
    sm[threadIdx.x] = s;
    __syncthreads();
    for (int off = 128; off; off >>= 1) {
        if (threadIdx.x < off) sm[threadIdx.x] += sm[threadIdx.x + off];
        __syncthreads();
    }
    if (!threadIdx.x) part[blockIdx.x] = sm[0];
}

__global__ void k_red2(const float* __restrict__ part, float* __restrict__ out,
                       int nb, float inv) {
    __shared__ float sm[256];
    int tid = threadIdx.x;
    float s = 0.f;
    for (int i = tid; i < nb; i += 256) s += part[i];
    sm[tid] = s;
    __syncthreads();
    for (int off = 128; off; off >>= 1) {
        if (tid < off) sm[tid] += sm[tid + off];
        __syncthreads();
    }
    if (!tid) out[0] = sm[0] * inv;
}

extern "C" void kernel_launch(void* const* d_in, const int* in_sizes, int n_in,
                              void* d_out, int out_size, void* d_ws, size_t ws_size,
                              hipStream_t stream) {
    const float* x  = (const float*)d_in[0];
    const float* gt = (const float*)d_in[1];

    float4* nrm4 = (float4*)d_ws;                           // 21.0 MB
    float* cost  = (float*)(nrm4 + (size_t)2 * B * 2 * HW); // 83.9 MB
    float* disp  = cost + (size_t)B * D * HW;               // 2.6 MB
    float* part  = disp + (size_t)2 * B * HW;               // 2560 floats

    constexpr int NPIX_BLKS = (B * HW + 255) / 256;         // 2560

    k_norm<<<(2 * B * HW + 255) / 256, 256, 0, stream>>>(x, gt, nrm4);

    k_cost<<<B * NSEG * D, 512, 0, stream>>>(nrm4, cost, 0);
    k_argmin0<<<NPIX_BLKS, 256, 0, stream>>>(cost, disp);
    k_cost<<<B * NSEG * D, 512, 0, stream>>>(nrm4, cost, 1);
    k_argmin1<<<NPIX_BLKS, 256, 0, stream>>>(cost, disp, part);

    k_red2<<<1, 256, 0, stream>>>(part, (float*)d_out, NPIX_BLKS, 1.f / (float)(B * HW));
}